// Round 5
// baseline (276.450 us; speedup 1.0000x reference)
//
#include <hip/hip_runtime.h>
#include <hip/hip_bf16.h>
#include <hip/hip_cooperative_groups.h>
#include <cstdint>

// Problem (all inputs/outputs fp32):
//   out[8192][2048] = X[8192][2048] @ Weff[2048][2048]
//   Weff[k][n] = W[k][n] + SCALE * sum_r A[k][r]*Bk[r][n], SCALE = 4/4 = 1.0
//
// R4 post-mortem: total ≈ gemm + 121 µs CONSTANT across R0-R4. prep_all's
// traffic (~120 MB) can only account for ~25 µs -> ~95 µs is launch/bubble
// overhead of the 2-kernel pipeline. R5: ONE cooperative launch:
//   phase A (prep, distributed over 256 blocks): fp32 X -> bf16 Xb;
//           (W + A@Bk)^T -> bf16 Wt [N][K] (4x 64x64 tiles per block)
//   grid.sync()  [cooperative; device-scope fence for cross-XCD visibility]
//   phase B: R4 rotated 8-phase 256x256 gemm, counted vmcnt, setprio.
//   sched_barrier(0) removed from MMA (it pinned reads after the MFMA burst,
//   serializing LDS vs MFMA pipes -- the R4 lesson).
// Fallback: if cooperative launch unavailable, two-kernel path (prep_all +
// gemm_8ph) identical to R4.
//
// Rotated ledger (unchanged from R4, correctness-proven):
//   P2:MMA q00/b0 rd B1->b1 | P3:q01/b1 rd A1 st s1 | P4:q11/b1 st s2 |
//   P5:q10/b0 VMW(6) rd A0,B0 st s3 | P6:q00/b0 rd B1 st s4 |
//   P7:q01/b1 VMW(8) rd A1 st s5,s6 | P8:q11/b1 st s7 |
//   P1':q10/b0 VMW(6) rd A0,B0 st s8
// Peeled last iter: VMW(4)@P5, VMW(0)@P6, stores by quadrant P6..P9.
// Round-4 lesson kept: do NOT read fp32 X inside the gemm K-loop.

namespace cg = cooperative_groups;

using bf16 = __hip_bfloat16;
typedef __attribute__((ext_vector_type(8))) __bf16 bf16x8;
typedef __attribute__((ext_vector_type(4))) float f32x4;

constexpr int Mdim = 8192;   // B*S
constexpr int Ndim = 2048;   // NH*HD
constexpr int Kdim = 2048;   // H
constexpr float SCALE = 1.0f;  // ALPHA/RANK = 4/4

constexpr int BM = 256, BN = 256, BK = 64;
constexpr int NT2 = Kdim / (2 * BK);                   // 16 iterations
constexpr int CVT_BLOCKS = (Mdim * Kdim) / (256 * 8);  // 8192 (fallback)
constexpr int PREP_BLOCKS = (Ndim / 64) * (Kdim / 64); // 1024 (fallback)

__device__ __forceinline__ void gload_lds16(const void* g, void* l) {
  __builtin_amdgcn_global_load_lds(
      (const __attribute__((address_space(1))) uint32_t*)g,
      (__attribute__((address_space(3))) uint32_t*)l,
      16, 0, 0);
}

__device__ __forceinline__ uint16_t f2bf(float f) {
  return __bfloat16_as_ushort(__float2bfloat16(f));
}

// ---------------- shared gemm body (Wt is Weff^T, K-major) ----------------
#define FENCE() asm volatile("" ::: "memory")
#define VMW(N)  asm volatile("s_waitcnt vmcnt(" #N ")" ::: "memory")
#define LGKM8() asm volatile("s_waitcnt lgkmcnt(8)" ::: "memory")
#define PH()                                                                   \
  do {                                                                         \
    FENCE();                                                                   \
    __builtin_amdgcn_s_barrier();                                              \
    FENCE();                                                                   \
  } while (0)

__device__ __forceinline__ void gemm_body(const uint16_t* __restrict__ X,
                                          const uint16_t* __restrict__ Wt,
                                          float* __restrict__ out,
                                          uint16_t* lds) {
  const int t = threadIdx.x;
  const int wave = t >> 6, lane = t & 63;
  const int wm = wave >> 2, wn = wave & 3;   // 2 x 4 wave grid
  const int l15 = lane & 15, kg = lane >> 4;
  const int sw = l15 & 7;

  // Bijective XCD patch swizzle: 256 blocks, 8 XCDs x 32 blocks.
  const int lid = blockIdx.x;                 // 0..255
  const int xcd = lid & 7, loc = lid >> 3;    // loc 0..31
  const int by = xcd * 4 + (loc & 3);         // 0..31
  const int bx = loc >> 2;                    // 0..7
  const int m0 = by * BM, n0 = bx * BN;

  const uint16_t* Ag = X + (size_t)m0 * Kdim;
  const uint16_t* Bg = Wt + (size_t)n0 * Kdim;

  // staging: slot = 8 rows x 64 cols (1 KB); wave w owns slots {2w,2w+1}.
  // Source chunk col XOR-swizzled -> linear LDS holds phys p = c ^ (row&7).
  const int r8 = lane >> 3;
  const int gc = (lane & 7) ^ r8;
  const int slot0 = wave * 2, slot1 = slot0 + 1;
  const size_t go0 = (size_t)(slot0 * 8 + r8) * Kdim + gc * 8;
  const size_t go1 = (size_t)(slot1 * 8 + r8) * Kdim + gc * 8;

  int aE[2], bE[2];
#pragma unroll
  for (int s2 = 0; s2 < 2; ++s2) {
    const int p = (s2 * 4 + kg) ^ sw;
    aE[s2] = (wm * 64 + l15) * 64 + p * 8;
    bE[s2] = (wn * 32 + l15) * 64 + p * 8;
  }

#define STAGE_A(buf, h, kt)                                                    \
  do {                                                                         \
    gload_lds16(Ag + go0 + (size_t)(h) * 128 * Kdim + (kt),                    \
                &lds[(buf) * 32768 + (h) * 8192 + slot0 * 512]);               \
    gload_lds16(Ag + go1 + (size_t)(h) * 128 * Kdim + (kt),                    \
                &lds[(buf) * 32768 + (h) * 8192 + slot1 * 512]);               \
  } while (0)
#define STAGE_B(buf, h, kt)                                                    \
  do {                                                                         \
    gload_lds16(Bg + go0 + (size_t)(h) * 128 * Kdim + (kt),                    \
                &lds[(buf) * 32768 + 16384 + (h) * 8192 + slot0 * 512]);       \
    gload_lds16(Bg + go1 + (size_t)(h) * 128 * Kdim + (kt),                    \
                &lds[(buf) * 32768 + 16384 + (h) * 8192 + slot1 * 512]);       \
  } while (0)

  bf16x8 a[4][2], b0[2][2], b1[2][2];
  f32x4 acc[8][4] = {};

#define READ_A(QM, buf)                                                        \
  do {                                                                         \
    _Pragma("unroll") for (int ii = 0; ii < 4; ++ii)                           \
        _Pragma("unroll") for (int s2 = 0; s2 < 2; ++s2)                       \
            a[ii][s2] = *reinterpret_cast<const bf16x8*>(                      \
                &lds[(buf) * 32768 + (QM) * 8192 + ii * 1024 + aE[s2]]);       \
  } while (0)
#define READ_B(QN, buf, dst)                                                   \
  do {                                                                         \
    _Pragma("unroll") for (int jj = 0; jj < 2; ++jj)                           \
        _Pragma("unroll") for (int s2 = 0; s2 < 2; ++s2)                       \
            dst[jj][s2] = *reinterpret_cast<const bf16x8*>(                    \
                &lds[(buf) * 32768 + 16384 + (QN) * 8192 + jj * 1024 +         \
                     bE[s2]]);                                                 \
  } while (0)
#define MMA(QM, QN, barr)                                                      \
  do {                                                                         \
    __builtin_amdgcn_s_setprio(1);                                             \
    _Pragma("unroll") for (int s2 = 0; s2 < 2; ++s2)                           \
        _Pragma("unroll") for (int ii = 0; ii < 4; ++ii)                       \
            _Pragma("unroll") for (int jj = 0; jj < 2; ++jj)                   \
                acc[(QM) * 4 + ii][(QN) * 2 + jj] =                            \
                    __builtin_amdgcn_mfma_f32_16x16x32_bf16(                   \
                        a[ii][s2], barr[jj][s2],                               \
                        acc[(QM) * 4 + ii][(QN) * 2 + jj], 0, 0, 0);           \
    __builtin_amdgcn_s_setprio(0);                                             \
  } while (0)
#define STORE_Q(QM, QN)                                                        \
  do {                                                                         \
    _Pragma("unroll") for (int ii = 0; ii < 4; ++ii) {                         \
      const int mb = m0 + (QM) * 128 + wm * 64 + ii * 16 + kg * 4;             \
      _Pragma("unroll") for (int jj = 0; jj < 2; ++jj) {                       \
        const int n = n0 + (QN) * 128 + wn * 32 + jj * 16 + l15;               \
        _Pragma("unroll") for (int r = 0; r < 4; ++r)                          \
            out[(size_t)(mb + r) * Ndim + n] =                                 \
                acc[(QM) * 4 + ii][(QN) * 2 + jj][r];                          \
      }                                                                        \
    }                                                                          \
  } while (0)

  // ---- prologue: buf0{B0,A0,B1,A1}, buf1{B0,A0,B1} (FIFO order matters) ----
  STAGE_B(0, 0, 0); STAGE_A(0, 0, 0); STAGE_B(0, 1, 0); STAGE_A(0, 1, 0);
  FENCE();
  STAGE_B(1, 0, BK); STAGE_A(1, 0, BK); STAGE_B(1, 1, BK);
  FENCE();
  VMW(6); PH();
  READ_A(0, 0); READ_B(0, 0, b0);
  STAGE_A(1, 1, BK);

  // ---- steady loop: full iterations j = 0 .. NT2-2 ----
#pragma unroll 1
  for (int j = 0; j < NT2 - 1; ++j) {
    const int kn0 = j * 128 + 128;   // tile 2j+2 -> buf0
    const int kn1 = j * 128 + 192;   // tile 2j+3 -> buf1

    // P2
    PH(); MMA(0, 0, b0); READ_B(1, 0, b1);
    // P3
    PH(); MMA(0, 1, b1); READ_A(1, 0); STAGE_B(0, 0, kn0);          // s1
    // P4
    PH(); MMA(1, 1, b1); STAGE_A(0, 0, kn0);                        // s2
    // P5
    VMW(6); PH(); MMA(1, 0, b0);
    READ_A(0, 1); READ_B(0, 1, b0); STAGE_B(0, 1, kn0);             // s3
    // P6
    PH(); MMA(0, 0, b0); READ_B(1, 1, b1); STAGE_A(0, 1, kn0);      // s4
    // P7
    VMW(8); PH(); MMA(0, 1, b1);
    READ_A(1, 1); STAGE_B(1, 0, kn1); STAGE_A(1, 0, kn1);           // s5,s6
    // P8
    PH(); MMA(1, 1, b1); STAGE_B(1, 1, kn1);                        // s7
    // P1'
    VMW(6); PH(); MMA(1, 0, b0);
    READ_A(0, 0); READ_B(0, 0, b0); STAGE_A(1, 1, kn1);             // s8
  }

  // ---- peeled last iteration: no staging; stores overlap final phases ----
  PH(); MMA(0, 0, b0); READ_B(1, 0, b1);
  PH(); MMA(0, 1, b1); READ_A(1, 0);
  PH(); MMA(1, 1, b1);
  VMW(4); PH(); MMA(1, 0, b0); READ_A(0, 1); READ_B(0, 1, b0);
  VMW(0); PH(); MMA(0, 0, b0); READ_B(1, 1, b1); STORE_Q(0, 0);
  PH(); MMA(0, 1, b1); READ_A(1, 1); STORE_Q(0, 1);
  PH(); MMA(1, 1, b1); STORE_Q(1, 1);
  PH(); MMA(1, 0, b0); STORE_Q(1, 0);

#undef STAGE_A
#undef STAGE_B
#undef READ_A
#undef READ_B
#undef MMA
#undef STORE_Q
}

// ---------------- prep phase as a device function (fused path) ------------
__device__ __forceinline__ void prep_body_fused(const float* __restrict__ X,
                                                const float* __restrict__ W,
                                                const float* __restrict__ A,
                                                const float* __restrict__ Bk,
                                                uint16_t* __restrict__ Xb,
                                                uint16_t* __restrict__ Wt,
                                                uint16_t* lds) {
  const int t = threadIdx.x;       // 0..511
  const int b = blockIdx.x;        // 0..255

  // ---- fp32 X -> bf16 Xb: 16 units of 8 f32 per thread, lane-contiguous ----
  {
    const float4* Xv = (const float4*)X;
#pragma unroll 4
    for (int it = 0; it < 16; ++it) {
      const int u = b * 512 + t + it * (256 * 512);
      float4 a4 = Xv[u * 2 + 0];
      float4 b4 = Xv[u * 2 + 1];
      uint16_t o[8];
      o[0] = f2bf(a4.x); o[1] = f2bf(a4.y); o[2] = f2bf(a4.z); o[3] = f2bf(a4.w);
      o[4] = f2bf(b4.x); o[5] = f2bf(b4.y); o[6] = f2bf(b4.z); o[7] = f2bf(b4.w);
      *reinterpret_cast<uint4*>(Xb + (size_t)u * 8) = *reinterpret_cast<uint4*>(o);
    }
  }

  // ---- Weff^T = (W + A@Bk)^T: 4 tiles of 64x64 per block ----
  float* tile = (float*)lds;       // [64][65] floats = 16.6 KB (of 128 KB)
  const int tx = t & 63;
  const int ty = t >> 6;           // 0..7
  for (int tt = 0; tt < 4; ++tt) {
    const int pid = b * 4 + tt;    // 0..1023
    const int n0 = (pid & 31) * 64, k0 = (pid >> 5) * 64;
    const int n = n0 + tx;
    const float c0 = Bk[0 * Ndim + n];
    const float c1 = Bk[1 * Ndim + n];
    const float c2 = Bk[2 * Ndim + n];
    const float c3 = Bk[3 * Ndim + n];
    __syncthreads();               // tile reuse across tt
#pragma unroll
    for (int i = ty; i < 64; i += 8) {
      const int k = k0 + i;
      float w = W[(size_t)k * Ndim + n];
      w += SCALE * (A[k * 4 + 0] * c0 + A[k * 4 + 1] * c1 +
                    A[k * 4 + 2] * c2 + A[k * 4 + 3] * c3);
      tile[tx * 65 + i] = w;       // transposed into LDS
    }
    __syncthreads();
#pragma unroll
    for (int i = ty; i < 64; i += 8) {
      Wt[(size_t)(n0 + i) * Kdim + (k0 + tx)] = f2bf(tile[i * 65 + tx]);
    }
  }
}

// ---------------- fused cooperative kernel --------------------------------
__global__ __launch_bounds__(512, 2) void fused_all(
    const float* __restrict__ X, const float* __restrict__ W,
    const float* __restrict__ A, const float* __restrict__ Bk,
    uint16_t* __restrict__ Xb, uint16_t* __restrict__ Wt,
    float* __restrict__ out) {
  __shared__ uint16_t lds[65536];
  prep_body_fused(X, W, A, Bk, Xb, Wt, lds);
  __threadfence();                 // device-scope release (cross-XCD, G16)
  cg::this_grid().sync();
  gemm_body(Xb, Wt, out, lds);
}

// ---------------- fallback two-kernel path (identical to R4) --------------
__global__ void prep_all(const float* __restrict__ X,
                         const float* __restrict__ W,
                         const float* __restrict__ A,
                         const float* __restrict__ Bk,
                         uint16_t* __restrict__ Xb,
                         uint16_t* __restrict__ Wt) {
  __shared__ float tile[64][65];

  if (blockIdx.x < CVT_BLOCKS) {
    const int i = blockIdx.x * blockDim.x + threadIdx.x;
    const float4* Xv = (const float4*)X;
    float4 a = Xv[i * 2 + 0];
    float4 b = Xv[i * 2 + 1];
    uint16_t o[8];
    o[0] = f2bf(a.x); o[1] = f2bf(a.y); o[2] = f2bf(a.z); o[3] = f2bf(a.w);
    o[4] = f2bf(b.x); o[5] = f2bf(b.y); o[6] = f2bf(b.z); o[7] = f2bf(b.w);
    *reinterpret_cast<uint4*>(Xb + (size_t)i * 8) = *reinterpret_cast<uint4*>(o);
  } else {
    const int pid = blockIdx.x - CVT_BLOCKS;
    const int tx = threadIdx.x & 63;
    const int ty = threadIdx.x >> 6;
    const int n0 = (pid & 31) * 64, k0 = (pid >> 5) * 64;
    const int n = n0 + tx;
    const float b0 = Bk[0 * Ndim + n];
    const float b1 = Bk[1 * Ndim + n];
    const float b2 = Bk[2 * Ndim + n];
    const float b3 = Bk[3 * Ndim + n];
    for (int i = ty; i < 64; i += 4) {
      const int k = k0 + i;
      float w = W[(size_t)k * Ndim + n];
      w += SCALE * (A[k * 4 + 0] * b0 + A[k * 4 + 1] * b1 +
                    A[k * 4 + 2] * b2 + A[k * 4 + 3] * b3);
      tile[tx][i] = w;
    }
    __syncthreads();
    for (int i = ty; i < 64; i += 4) {
      Wt[(size_t)(n0 + i) * Kdim + (k0 + tx)] = f2bf(tile[i][tx]);
    }
  }
}

__global__ __launch_bounds__(512, 2) void gemm_8ph(
    const uint16_t* __restrict__ X, const uint16_t* __restrict__ Wt,
    float* __restrict__ out) {
  __shared__ uint16_t lds[65536];
  gemm_body(X, Wt, out, lds);
}

extern "C" void kernel_launch(void* const* d_in, const int* in_sizes, int n_in,
                              void* d_out, int out_size, void* d_ws, size_t ws_size,
                              hipStream_t stream) {
  const float* x  = (const float*)d_in[0];  // [4,2048,2048]
  const float* W  = (const float*)d_in[1];  // [2048,16,128]
  const float* A  = (const float*)d_in[2];  // [2048,4]
  const float* Bk = (const float*)d_in[3];  // [4,16,128]
  float* out = (float*)d_out;               // [4,2048,16,128] fp32

  uint16_t* Xb = (uint16_t*)d_ws;                                     // 32 MB
  uint16_t* Wt = (uint16_t*)((char*)d_ws + (size_t)Mdim * Kdim * 2);  // 8 MB

  static int coop_checked = 0, coop_ok = 0;
  if (!coop_checked) {
    int dev = 0;
    (void)hipGetDevice(&dev);
    int v = 0;
    if (hipDeviceGetAttribute(&v, hipDeviceAttributeCooperativeLaunch, dev) ==
        hipSuccess)
      coop_ok = v;
    coop_checked = 1;
  }

  bool launched = false;
  if (coop_ok) {
    void* args[] = {(void*)&x, (void*)&W, (void*)&A, (void*)&Bk,
                    (void*)&Xb, (void*)&Wt, (void*)&out};
    hipError_t e = hipLaunchCooperativeKernel(
        reinterpret_cast<void*>(fused_all), dim3(256), dim3(512), args, 0,
        stream);
    launched = (e == hipSuccess);
  }
  if (!launched) {
    prep_all<<<CVT_BLOCKS + PREP_BLOCKS, 256, 0, stream>>>(x, W, A, Bk, Xb, Wt);
    gemm_8ph<<<(Mdim / BM) * (Ndim / BN), 512, 0, stream>>>(Xb, Wt, out);
  }
}

// Round 6
// 190.680 us; speedup vs baseline: 1.4498x; 1.4498x over previous
//
#include <hip/hip_runtime.h>
#include <hip/hip_bf16.h>
#include <cstdint>

// Problem (all inputs/outputs fp32):
//   out[8192][2048] = X[8192][2048] @ Weff[2048][2048]
//   Weff[k][n] = W[k][n] + SCALE * sum_r A[k][r]*Bk[r][n], SCALE = 4/4 = 1.0
//
// Pipeline (2 launches):
//   prep_all: [blocks 0..8191] fp32 X -> bf16 Xb (d_ws)
//             [blocks 8192..9215] fp32 (W + A@Bk)^T -> bf16 Wt [N][K]
//   gemm_8ph: 256x256 tile, BK=64, 8 waves (2Mx4N), ROTATED 8-phase.
//
// R5 post-mortem (coop fusion): total-minus-dispatch stayed ~109 us with a
// SINGLE launch -> the ~110-120 us constant is harness reset/memset overhead,
// NOT per-launch cost. Fusion itself regressed ~85 us (prep at 256-block
// occupancy is latency-bound; grid.sync expensive). REVERTED to two-kernel.
// R6 delta vs R4: MMA's sched_barrier(0) REMOVED. R4's rotation was null
// because the pin kept all ds_reads AFTER the 16-MFMA burst, preserving the
// LDS<->MFMA serialization. Without it the compiler may interleave reads
// between MFMA issues (WAR resolves at issue; PH()'s memory clobber still
// blocks cross-barrier hoisting; reads are compiler loads -> auto-lgkmcnt).
//
// Rotated ledger (correctness-proven R4; stage slots s1..s8 load tiles
// 2j+2 (kn0), 2j+3 (kn1); 2 loads each; reads(p) feed MMA at p+1):
//   P2:MMA q00/b0 rd B1->b1 | P3:q01/b1 rd A1 st s1 | P4:q11/b1 st s2 |
//   P5:q10/b0 VMW(6) rd A0,B0 st s3 | P6:q00/b0 rd B1 st s4 |
//   P7:q01/b1 VMW(8) rd A1 st s5,s6 | P8:q11/b1 st s7 |
//   P1':q10/b0 VMW(6) rd A0,B0 st s8
// Steady FIFO: enter P2 with {s5..s8}(j-1)=8 outstanding. VMW(6)@P5 drains
// s5..s7(j-1) (5-6 phases old); VMW(8)@P7 drains s8(j-1); VMW(6)@P1' drains
// s1..s4(j) (3-6 phases old). WAR: every region restaged >=2 phases after
// its last read's consuming MMA (single barrier/phase happens-before chain).
// Peeled last iter: VMW(4)@P5, VMW(0)@P6, stores by quadrant P6..P9, no
// vm-waits after stores begin (stores count in vmcnt).
// Round-4 lesson kept: do NOT read fp32 X inside the gemm K-loop.

using bf16 = __hip_bfloat16;
typedef __attribute__((ext_vector_type(8))) __bf16 bf16x8;
typedef __attribute__((ext_vector_type(4))) float f32x4;

constexpr int Mdim = 8192;   // B*S
constexpr int Ndim = 2048;   // NH*HD
constexpr int Kdim = 2048;   // H
constexpr float SCALE = 1.0f;  // ALPHA/RANK = 4/4

constexpr int BM = 256, BN = 256, BK = 64;
constexpr int NT2 = Kdim / (2 * BK);                   // 16 iterations
constexpr int CVT_BLOCKS = (Mdim * Kdim) / (256 * 8);  // 8192
constexpr int PREP_BLOCKS = (Ndim / 64) * (Kdim / 64); // 1024

__device__ __forceinline__ void gload_lds16(const void* g, void* l) {
  __builtin_amdgcn_global_load_lds(
      (const __attribute__((address_space(1))) uint32_t*)g,
      (__attribute__((address_space(3))) uint32_t*)l,
      16, 0, 0);
}

__device__ __forceinline__ uint16_t f2bf(float f) {
  return __bfloat16_as_ushort(__float2bfloat16(f));
}

// ------------- prep_all: cvt_x (blocks<8192) + Weff^T build --------------
__global__ void prep_all(const float* __restrict__ X,
                         const float* __restrict__ W,
                         const float* __restrict__ A,
                         const float* __restrict__ Bk,
                         uint16_t* __restrict__ Xb,
                         uint16_t* __restrict__ Wt) {
  __shared__ float tile[64][65];  // used by prep part only (+1 pad)

  if (blockIdx.x < CVT_BLOCKS) {
    // ---- fp32 -> bf16, 8 elems/thread, float4 loads ----
    const int i = blockIdx.x * blockDim.x + threadIdx.x;
    const float4* Xv = (const float4*)X;
    float4 a = Xv[i * 2 + 0];
    float4 b = Xv[i * 2 + 1];
    uint16_t o[8];
    o[0] = f2bf(a.x); o[1] = f2bf(a.y); o[2] = f2bf(a.z); o[3] = f2bf(a.w);
    o[4] = f2bf(b.x); o[5] = f2bf(b.y); o[6] = f2bf(b.z); o[7] = f2bf(b.w);
    *reinterpret_cast<uint4*>(Xb + (size_t)i * 8) = *reinterpret_cast<uint4*>(o);
  } else {
    // ---- Weff^T = (W + A@Bk)^T, [N][K] bf16 ----
    const int pid = blockIdx.x - CVT_BLOCKS;       // 0..1023
    const int tx = threadIdx.x & 63;
    const int ty = threadIdx.x >> 6;
    const int n0 = (pid & 31) * 64, k0 = (pid >> 5) * 64;

    const int n = n0 + tx;
    const float b0 = Bk[0 * Ndim + n];
    const float b1 = Bk[1 * Ndim + n];
    const float b2 = Bk[2 * Ndim + n];
    const float b3 = Bk[3 * Ndim + n];

    for (int i = ty; i < 64; i += 4) {
      const int k = k0 + i;
      float w = W[(size_t)k * Ndim + n];
      w += SCALE * (A[k * 4 + 0] * b0 + A[k * 4 + 1] * b1 +
                    A[k * 4 + 2] * b2 + A[k * 4 + 3] * b3);
      tile[tx][i] = w;                       // transposed into LDS
    }
    __syncthreads();
    for (int i = ty; i < 64; i += 4) {
      Wt[(size_t)(n0 + i) * Kdim + (k0 + tx)] = f2bf(tile[i][tx]);
    }
  }
}

// ---------------- main GEMM: C = Xb @ Weff (Wt is Weff^T, K-major) --------
#define FENCE() asm volatile("" ::: "memory")
#define VMW(N)  asm volatile("s_waitcnt vmcnt(" #N ")" ::: "memory")
#define PH()                                                                   \
  do {                                                                         \
    FENCE();                                                                   \
    __builtin_amdgcn_s_barrier();                                              \
    FENCE();                                                                   \
  } while (0)

__global__ __launch_bounds__(512, 2) void gemm_8ph(
    const uint16_t* __restrict__ X, const uint16_t* __restrict__ Wt,
    float* __restrict__ out) {
  // LDS: [A0 | B0 | A1 | B1], 16384 uint16 each = 128 KiB total.
  __shared__ uint16_t lds[65536];

  const int t = threadIdx.x;
  const int wave = t >> 6, lane = t & 63;
  const int wm = wave >> 2, wn = wave & 3;   // 2 x 4 wave grid
  const int l15 = lane & 15, kg = lane >> 4;
  const int sw = l15 & 7;

  // Bijective XCD patch swizzle: 256 blocks, 8 XCDs x 32 blocks.
  const int lid = blockIdx.x;                 // 0..255
  const int xcd = lid & 7, loc = lid >> 3;    // loc 0..31
  const int by = xcd * 4 + (loc & 3);         // 0..31
  const int bx = loc >> 2;                    // 0..7
  const int m0 = by * BM, n0 = bx * BN;

  const uint16_t* Ag = X + (size_t)m0 * Kdim;
  const uint16_t* Bg = Wt + (size_t)n0 * Kdim;

  // staging: slot = 8 rows x 64 cols (1 KB); wave w owns slots {2w,2w+1}.
  // Source chunk col XOR-swizzled -> linear LDS holds phys p = c ^ (row&7).
  const int r8 = lane >> 3;
  const int gc = (lane & 7) ^ r8;
  const int slot0 = wave * 2, slot1 = slot0 + 1;
  const size_t go0 = (size_t)(slot0 * 8 + r8) * Kdim + gc * 8;
  const size_t go1 = (size_t)(slot1 * 8 + r8) * Kdim + gc * 8;

  // per-lane LDS element offsets for frag reads (per k-step s2)
  int aE[2], bE[2];
#pragma unroll
  for (int s2 = 0; s2 < 2; ++s2) {
    const int p = (s2 * 4 + kg) ^ sw;
    aE[s2] = (wm * 64 + l15) * 64 + p * 8;
    bE[s2] = (wn * 32 + l15) * 64 + p * 8;
  }

#define STAGE_A(buf, h, kt)                                                    \
  do {                                                                         \
    gload_lds16(Ag + go0 + (size_t)(h) * 128 * Kdim + (kt),                    \
                &lds[(buf) * 32768 + (h) * 8192 + slot0 * 512]);               \
    gload_lds16(Ag + go1 + (size_t)(h) * 128 * Kdim + (kt),                    \
                &lds[(buf) * 32768 + (h) * 8192 + slot1 * 512]);               \
  } while (0)
#define STAGE_B(buf, h, kt)                                                    \
  do {                                                                         \
    gload_lds16(Bg + go0 + (size_t)(h) * 128 * Kdim + (kt),                    \
                &lds[(buf) * 32768 + 16384 + (h) * 8192 + slot0 * 512]);       \
    gload_lds16(Bg + go1 + (size_t)(h) * 128 * Kdim + (kt),                    \
                &lds[(buf) * 32768 + 16384 + (h) * 8192 + slot1 * 512]);       \
  } while (0)

  bf16x8 a[4][2], b0[2][2], b1[2][2];
  f32x4 acc[8][4] = {};

#define READ_A(QM, buf)                                                        \
  do {                                                                         \
    _Pragma("unroll") for (int ii = 0; ii < 4; ++ii)                           \
        _Pragma("unroll") for (int s2 = 0; s2 < 2; ++s2)                       \
            a[ii][s2] = *reinterpret_cast<const bf16x8*>(                      \
                &lds[(buf) * 32768 + (QM) * 8192 + ii * 1024 + aE[s2]]);       \
  } while (0)
#define READ_B(QN, buf, dst)                                                   \
  do {                                                                         \
    _Pragma("unroll") for (int jj = 0; jj < 2; ++jj)                           \
        _Pragma("unroll") for (int s2 = 0; s2 < 2; ++s2)                       \
            dst[jj][s2] = *reinterpret_cast<const bf16x8*>(                    \
                &lds[(buf) * 32768 + 16384 + (QN) * 8192 + jj * 1024 +         \
                     bE[s2]]);                                                 \
  } while (0)
// MMA uses fragments read LAST phase. NO sched_barrier: let the compiler
// interleave this phase's ds_reads between MFMA issues (R6 experiment).
#define MMA(QM, QN, barr)                                                      \
  do {                                                                         \
    __builtin_amdgcn_s_setprio(1);                                             \
    _Pragma("unroll") for (int s2 = 0; s2 < 2; ++s2)                           \
        _Pragma("unroll") for (int ii = 0; ii < 4; ++ii)                       \
            _Pragma("unroll") for (int jj = 0; jj < 2; ++jj)                   \
                acc[(QM) * 4 + ii][(QN) * 2 + jj] =                            \
                    __builtin_amdgcn_mfma_f32_16x16x32_bf16(                   \
                        a[ii][s2], barr[jj][s2],                               \
                        acc[(QM) * 4 + ii][(QN) * 2 + jj], 0, 0, 0);           \
    __builtin_amdgcn_s_setprio(0);                                             \
  } while (0)
// store one 128x128 output quadrant (this wave's 64x32 piece of it)
#define STORE_Q(QM, QN)                                                        \
  do {                                                                         \
    _Pragma("unroll") for (int ii = 0; ii < 4; ++ii) {                         \
      const int mb = m0 + (QM) * 128 + wm * 64 + ii * 16 + kg * 4;             \
      _Pragma("unroll") for (int jj = 0; jj < 2; ++jj) {                       \
        const int n = n0 + (QN) * 128 + wn * 32 + jj * 16 + l15;               \
        _Pragma("unroll") for (int r = 0; r < 4; ++r)                          \
            out[(size_t)(mb + r) * Ndim + n] =                                 \
                acc[(QM) * 4 + ii][(QN) * 2 + jj][r];                          \
      }                                                                        \
    }                                                                          \
  } while (0)

  // ---- prologue: buf0{B0,A0,B1,A1}, buf1{B0,A0,B1} (FIFO order matters) ----
  STAGE_B(0, 0, 0); STAGE_A(0, 0, 0); STAGE_B(0, 1, 0); STAGE_A(0, 1, 0);
  FENCE();
  STAGE_B(1, 0, BK); STAGE_A(1, 0, BK); STAGE_B(1, 1, BK);
  FENCE();
  // "P1(0)": publish buf0; read A0,B0; stage s8(-1)=buf1.A1. No MMA.
  VMW(6); PH();
  READ_A(0, 0); READ_B(0, 0, b0);
  STAGE_A(1, 1, BK);

  // ---- steady loop: full iterations j = 0 .. NT2-2 ----
#pragma unroll 1
  for (int j = 0; j < NT2 - 1; ++j) {
    const int kn0 = j * 128 + 128;   // tile 2j+2 -> buf0
    const int kn1 = j * 128 + 192;   // tile 2j+3 -> buf1

    // P2
    PH(); MMA(0, 0, b0); READ_B(1, 0, b1);
    // P3
    PH(); MMA(0, 1, b1); READ_A(1, 0); STAGE_B(0, 0, kn0);          // s1
    // P4
    PH(); MMA(1, 1, b1); STAGE_A(0, 0, kn0);                        // s2
    // P5
    VMW(6); PH(); MMA(1, 0, b0);
    READ_A(0, 1); READ_B(0, 1, b0); STAGE_B(0, 1, kn0);             // s3
    // P6
    PH(); MMA(0, 0, b0); READ_B(1, 1, b1); STAGE_A(0, 1, kn0);      // s4
    // P7
    VMW(8); PH(); MMA(0, 1, b1);
    READ_A(1, 1); STAGE_B(1, 0, kn1); STAGE_A(1, 0, kn1);           // s5,s6
    // P8
    PH(); MMA(1, 1, b1); STAGE_B(1, 1, kn1);                        // s7
    // P1'
    VMW(6); PH(); MMA(1, 0, b0);
    READ_A(0, 0); READ_B(0, 0, b0); STAGE_A(1, 1, kn1);             // s8
  }

  // ---- peeled last iteration: no staging; stores overlap final phases ----
  PH(); MMA(0, 0, b0); READ_B(1, 0, b1);
  PH(); MMA(0, 1, b1); READ_A(1, 0);
  PH(); MMA(1, 1, b1);
  // P5: publish buf1.{B0,A0} (s5,s6 issued 6 phases ago -> free)
  VMW(4); PH(); MMA(1, 0, b0); READ_A(0, 1); READ_B(0, 1, b0);
  // P6: drain s7,s8; stores begin, no vm-waits after this point
  VMW(0); PH(); MMA(0, 0, b0); READ_B(1, 1, b1); STORE_Q(0, 0);
  PH(); MMA(0, 1, b1); READ_A(1, 1); STORE_Q(0, 1);
  PH(); MMA(1, 1, b1); STORE_Q(1, 1);
  PH(); MMA(1, 0, b0); STORE_Q(1, 0);

#undef STAGE_A
#undef STAGE_B
#undef READ_A
#undef READ_B
#undef MMA
#undef STORE_Q
}

extern "C" void kernel_launch(void* const* d_in, const int* in_sizes, int n_in,
                              void* d_out, int out_size, void* d_ws, size_t ws_size,
                              hipStream_t stream) {
  const float* x  = (const float*)d_in[0];  // [4,2048,2048]
  const float* W  = (const float*)d_in[1];  // [2048,16,128]
  const float* A  = (const float*)d_in[2];  // [2048,4]
  const float* Bk = (const float*)d_in[3];  // [4,16,128]
  float* out = (float*)d_out;               // [4,2048,16,128] fp32

  uint16_t* Xb = (uint16_t*)d_ws;                                     // 32 MB
  uint16_t* Wt = (uint16_t*)((char*)d_ws + (size_t)Mdim * Kdim * 2);  // 8 MB

  // fused: X fp32->bf16  +  Weff^T build
  prep_all<<<CVT_BLOCKS + PREP_BLOCKS, 256, 0, stream>>>(x, W, A, Bk, Xb, Wt);

  // main GEMM: 256 blocks (1/CU), 512 threads, rotated 8-phase schedule
  gemm_8ph<<<(Mdim / BM) * (Ndim / BN), 512, 0, stream>>>(Xb, Wt, out);
}